// Round 1
// baseline (571.559 us; speedup 1.0000x reference)
//
#include <hip/hip_runtime.h>

// BlurPool3d: x (4,64,32,112,112) f32, replicate-pad 1, depthwise 3x3x3
// binomial [1,2,1]/4 separable blur, stride 2 -> out (4,64,16,56,56) f32.
// Memory-bound: 411 MB in + 51 MB out => ~75-85 us floor at ~5.5-6.3 TB/s.

#define IN_D 32
#define IN_H 112
#define IN_W 112
#define OUT_D 16
#define OUT_H 56
#define OUT_W 56

__global__ __launch_bounds__(256) void blurpool3d_kernel(
    const float* __restrict__ x, float* __restrict__ out, int total)
{
    int idx = blockIdx.x * 256 + threadIdx.x;
    if (idx >= total) return;

    // Decode flat output index: (((n*C + c)*OD + od)*OH + oh)*OW + ow
    int ow = idx % OUT_W;
    int t  = idx / OUT_W;
    int oh = t % OUT_H;
    t /= OUT_H;
    int od = t % OUT_D;
    int nc = t / OUT_D;   // n*C + c  (0..255)

    // Input window center indices. High edge never clamps (2*od+1 <= 31 etc.)
    int iw1 = 2 * ow;
    int ih1 = 2 * oh;
    int id1 = 2 * od;
    int iw0 = max(iw1 - 1, 0);
    int ih0 = max(ih1 - 1, 0);
    int id0 = max(id1 - 1, 0);

    const float* p = x + (size_t)nc * (IN_D * IN_H * IN_W);

    float dsum = 0.0f;
#pragma unroll
    for (int kd = 0; kd < 3; ++kd) {
        int id = (kd == 0) ? id0 : (kd == 1 ? id1 : id1 + 1);
        const float* pd = p + (size_t)id * (IN_H * IN_W);
        float hsum = 0.0f;
#pragma unroll
        for (int kh = 0; kh < 3; ++kh) {
            int ih = (kh == 0) ? ih0 : (kh == 1 ? ih1 : ih1 + 1);
            const float* ph = pd + ih * IN_W;
            float a = ph[iw0];
            float b = ph[iw1];
            float c = ph[iw1 + 1];
            float wsum = a + 2.0f * b + c;          // [1,2,1] along W
            hsum += (kh == 1 ? 2.0f : 1.0f) * wsum; // [1,2,1] along H
        }
        dsum += (kd == 1 ? 2.0f : 1.0f) * hsum;     // [1,2,1] along D
    }
    out[idx] = dsum * (1.0f / 64.0f);               // /4 per dim
}

extern "C" void kernel_launch(void* const* d_in, const int* in_sizes, int n_in,
                              void* d_out, int out_size, void* d_ws, size_t ws_size,
                              hipStream_t stream)
{
    const float* x = (const float*)d_in[0];
    float* out = (float*)d_out;
    int total = out_size;  // 4*64*16*56*56 = 12,845,056
    int grid = (total + 255) / 256;
    blurpool3d_kernel<<<grid, 256, 0, stream>>>(x, out, total);
}

// Round 2
// 557.109 us; speedup vs baseline: 1.0259x; 1.0259x over previous
//
#include <hip/hip_runtime.h>

// BlurPool3d: x (4,64,32,112,112) f32, replicate-pad 1, depthwise 3x3x3
// binomial [1,2,1]/4 separable blur, stride 2 -> out (4,64,16,56,56) f32.
// Memory-bound: 411 MB in + 51 MB out => ~75-85 us floor at ~6.3 TB/s.
//
// R1: 4 outputs/thread along W. Two aligned float4 loads + 1 clamped scalar
// cover the 9-float input window per row; 9 rows (3 ih x 3 id) per thread.
// float4 output store. All global traffic 16B-coalesced.

#define IN_D 32
#define IN_H 112
#define IN_W 112
#define OUT_D 16
#define OUT_H 56
#define OUT_W 56
#define OW4 14          // 56 / 4 outputs per thread

__global__ __launch_bounds__(256) void blurpool3d_kernel(
    const float* __restrict__ x, float* __restrict__ out, int total4)
{
    int idx = blockIdx.x * 256 + threadIdx.x;
    if (idx >= total4) return;

    // Decode: idx -> (nc, od, oh, ow4)
    int t   = idx;
    int ow4 = t % OW4;  t /= OW4;
    int oh  = t % OUT_H; t /= OUT_H;
    int od  = t % OUT_D;
    int nc  = t / OUT_D;            // n*C + c, 0..255

    int iwbase = ow4 * 8;           // aligned start of the 8-float segment
    int iwl    = max(iwbase - 1, 0);// clamped left scalar index
    int ih1 = 2 * oh;
    int id1 = 2 * od;
    int ih0 = max(ih1 - 1, 0);
    int id0 = max(id1 - 1, 0);

    const float* p = x + (size_t)nc * (IN_D * IN_H * IN_W);

    float acc0 = 0.f, acc1 = 0.f, acc2 = 0.f, acc3 = 0.f;

#pragma unroll
    for (int kd = 0; kd < 3; ++kd) {
        int id = (kd == 0) ? id0 : (kd == 1 ? id1 : id1 + 1);
        const float* pd = p + (size_t)id * (IN_H * IN_W);
        float wd = (kd == 1) ? 2.0f : 1.0f;
#pragma unroll
        for (int kh = 0; kh < 3; ++kh) {
            int ih = (kh == 0) ? ih0 : (kh == 1 ? ih1 : ih1 + 1);
            const float* row = pd + ih * IN_W;
            float wt = wd * ((kh == 1) ? 2.0f : 1.0f);

            float4 v0 = *(const float4*)(row + iwbase);
            float4 v1 = *(const float4*)(row + iwbase + 4);
            float left = row[iwl];

            // window e[k] = w(iwbase + k - 1); output j uses e[2j..2j+2]
            float w0 = left + 2.0f * v0.x + v0.y;
            float w1 = v0.y + 2.0f * v0.z + v0.w;
            float w2 = v0.w + 2.0f * v1.x + v1.y;
            float w3 = v1.y + 2.0f * v1.z + v1.w;

            acc0 = fmaf(wt, w0, acc0);
            acc1 = fmaf(wt, w1, acc1);
            acc2 = fmaf(wt, w2, acc2);
            acc3 = fmaf(wt, w3, acc3);
        }
    }

    float4 r;
    r.x = acc0 * (1.0f / 64.0f);
    r.y = acc1 * (1.0f / 64.0f);
    r.z = acc2 * (1.0f / 64.0f);
    r.w = acc3 * (1.0f / 64.0f);

    size_t obase = (size_t)idx * 4;   // flat output index (contiguous by construction)
    *(float4*)(out + obase) = r;
}

extern "C" void kernel_launch(void* const* d_in, const int* in_sizes, int n_in,
                              void* d_out, int out_size, void* d_ws, size_t ws_size,
                              hipStream_t stream)
{
    const float* x = (const float*)d_in[0];
    float* out = (float*)d_out;
    int total4 = out_size / 4;        // 3,211,264 threads, 4 outputs each
    int grid = (total4 + 255) / 256;
    blurpool3d_kernel<<<grid, 256, 0, stream>>>(x, out, total4);
}